// Round 4
// baseline (854.246 us; speedup 1.0000x reference)
//
#include <hip/hip_runtime.h>
#include <math.h>

#define BB 32
#define LL 40
#define DD 128
#define NSB 64                        // 2 seq * 32 batch
#define NU  (NSB * LL)                // 2560 (sb,t) pairs
#define PLANE (DD * DD)               // 16384
#define SLAB ((size_t)NSB * PLANE)    // u16 elements per t-slab (2 MB)

typedef unsigned short u16;

__device__ __forceinline__ u16 f2bf(float f) {
    union { float f; unsigned u; } v; v.f = f;
    unsigned u = v.u;
    u += 0x7fff + ((u >> 16) & 1);    // RNE
    return (u16)(u >> 16);
}
__device__ __forceinline__ float bf2f(u16 b) {
    union { unsigned u; float f; } v; v.u = ((unsigned)b) << 16;
    return v.f;
}
__device__ __forceinline__ float sigm(float x)  { return 1.f / (1.f + __expf(-x)); }
// tanh(x) = 2*sigmoid(2x)-1 ; safe at extremes (exp->inf => -1, exp->0 => 1)
__device__ __forceinline__ float tanhs(float x) { return 2.f / (1.f + __expf(-2.f * x)) - 1.f; }

// ---------------- prep: xe rows + inverse squared norms ----------------
__global__ void prep_kernel(const int* __restrict__ q, const int* __restrict__ a,
                            const float* __restrict__ embed,
                            float* __restrict__ xe_all, float* __restrict__ inv_all) {
    int u = blockIdx.x * 4 + (threadIdx.x >> 6);
    int lane = threadIdx.x & 63;
    if (u >= NU) return;
    int sb = u / LL, t = u % LL;
    int s = sb >> 5, b = sb & 31;
    const int* idx = s ? a : q;
    int e = idx[b * LL + t];
    const float* row = embed + (size_t)e * DD;
    float v0 = row[lane], v1 = row[lane + 64];
    xe_all[(size_t)u * DD + lane] = v0;
    xe_all[(size_t)u * DD + lane + 64] = v1;
    float d = v0 * v0 + v1 * v1;
    #pragma unroll
    for (int o = 32; o; o >>= 1) d += __shfl_down(d, o);
    if (lane == 0) inv_all[u] = 1.f / (d + 1e-4f);
}

// ---------------- layer1 rows 0..62: separable density conv (rank-1 input) ----------------
// grid (8, NSB), block (128, 8)
__global__ __launch_bounds__(1024)
void lev0_l1_kernel(const float* __restrict__ xe_all, const float* __restrict__ inv_all,
                    const float* __restrict__ conv_w, const float* __restrict__ conv_b,
                    u16* __restrict__ h1) {
    const int chunk = blockIdx.x, sb = blockIdx.y;
    const int r0 = chunk * 8;
    const int nr = min(8, 63 - r0);
    const int tx = threadIdx.x, ty = threadIdx.y;
    const int tid = ty * 128 + tx;
    __shared__ float xe_s[DD];
    __shared__ float us[8][12];
    __shared__ float wls[48], bls[4];
    if (tid < 48) wls[tid] = conv_w[tid];
    if (tid < 4)  bls[tid] = conv_b[tid];
    const float* xe_u = xe_all + (size_t)(sb * LL) * DD;
    const float* inv_u = inv_all + sb * LL;
    u16* hp = h1 + SLAB + (size_t)sb * PLANE + (size_t)(r0 + ty) * DD + tx;  // slab t+1
    const bool act = ty < nr;
    float c_reg = 0.f;
    for (int t = 0; t < LL; ++t) {
        __syncthreads();
        if (tid < DD) xe_s[tid] = xe_u[tid];
        __syncthreads();
        if (tid < 12 * nr) {
            int iy = tid / 12, k = tid - iy * 12;
            int g = k / 3, kw = k - g * 3;
            int base = 2 * (r0 + iy) - 1;
            float s = 0.f;
            #pragma unroll
            for (int kh = 0; kh < 4; ++kh) {
                int r = base + kh;
                float v = (r >= 0 && r < DD) ? xe_s[r] : 0.f;
                s += wls[g * 12 + kh * 3 + kw] * v;
            }
            us[iy][k] = s;
        }
        __syncthreads();
        if (act) {
            float invv = inv_u[t];
            float xl = tx > 0 ? xe_s[tx - 1] : 0.f;
            float xm = xe_s[tx];
            float xr = tx < 127 ? xe_s[tx + 1] : 0.f;
            float a0 = bls[0] + invv * (us[ty][0] * xl + us[ty][1]  * xm + us[ty][2]  * xr);
            float a1 = bls[1] + invv * (us[ty][3] * xl + us[ty][4]  * xm + us[ty][5]  * xr);
            float a2 = bls[2] + invv * (us[ty][6] * xl + us[ty][7]  * xm + us[ty][8]  * xr);
            float a3 = bls[3] + invv * (us[ty][9] * xl + us[ty][10] * xm + us[ty][11] * xr);
            float fg = sigm(a0), ig = sigm(a1), og = sigm(a2), cs = tanhs(a3);
            c_reg = fg * c_reg + ig * cs;
            *hp = f2bf(og * tanhs(c_reg));
        }
        hp += SLAB;
        xe_u += DD;
    }
}

// ---------------- generic level sweep (serial t, direct 4x3 conv) ----------------
// Computes rows [row0_lev, row0_lev+nrows_lev) of one layer; depends only on
// strictly-lower rows at t-1 (already in h_own) and, for layer2, h1[t].
// grid (ceil(nrows/8), NSB), block (128, 8).
__global__ __launch_bounds__(1024)
void conv_level_kernel(const float* __restrict__ xe_all, const float* __restrict__ inv_all,
                       const float* __restrict__ conv_w, const float* __restrict__ conv_b,
                       const u16* __restrict__ xt_buf,  // layer2: h1; layer1: null (density)
                       u16* __restrict__ h_own,
                       float* __restrict__ pool,        // layer2 only
                       int layer, int row0_lev, int nrows_lev) {
    const int chunk = blockIdx.x, sb = blockIdx.y;
    const int row0 = row0_lev + chunk * 8;
    const int nr = min(8, row0_lev + nrows_lev - row0);
    const int tx = threadIdx.x, ty = threadIdx.y;
    const int tid = ty * 128 + tx;
    __shared__ float win[18][130];
    __shared__ float wls[48], bls[4];
    if (tid < 48) wls[tid] = conv_w[layer * 48 + tid];
    if (tid < 4)  bls[tid] = conv_b[layer * 4 + tid];
    if (tid < 36) win[tid >> 1][(tid & 1) ? 129 : 0] = 0.f;   // col pads

    const int rfirst = 2 * row0 - 1;
    const int rcount = 2 * nr + 2;

    // precompute per-thread staged-row slots (constant across t)
    const u16* sp[3]; const float* xr_p[3]; int md[3];   // 0 skip, 1 load, 2 density
    #pragma unroll
    for (int s = 0; s < 3; ++s) {
        int rr = (s < 2) ? (ty + 8 * s) : (16 + ty);
        bool valid = (s < 2 || ty < 2) && (rr < rcount);
        md[s] = 0; sp[s] = nullptr; xr_p[s] = nullptr;
        if (valid) {
            int cr = rfirst + rr;
            if (cr >= 0 && cr < 2 * DD) {
                if (cr < DD) {
                    if (xt_buf) { md[s] = 1; sp[s] = xt_buf + SLAB + (size_t)sb * PLANE + (size_t)cr * DD + tx; }
                    else        { md[s] = 2; xr_p[s] = xe_all + (size_t)(sb * LL) * DD + cr; }
                } else {
                    // own h at t-1: slab t (leading slab 0 is zeroed => t=0 reads zeros)
                    md[s] = 1; sp[s] = h_own + (size_t)sb * PLANE + (size_t)(cr - DD) * DD + tx;
                }
            } else {
                win[rr][tx + 1] = 0.f;   // constant zero row (height pad)
            }
        }
    }
    const float* xe_me = xe_all + (size_t)(sb * LL) * DD + tx;
    const float* inv_u = inv_all + sb * LL;
    const bool any_dens = (layer == 0) && (rfirst < DD);

    u16* hp = h_own + SLAB + (size_t)sb * PLANE + (size_t)(row0 + ty) * DD + tx;
    const bool act = ty < nr;
    float c_reg = 0.f, pr = -1e30f;

    for (int t = 0; t < LL; ++t) {
        float invv = any_dens ? inv_u[t] : 0.f;
        __syncthreads();                       // prior reads of win done
        #pragma unroll
        for (int s = 0; s < 3; ++s) {
            int rr = (s < 2) ? (ty + 8 * s) : (16 + ty);
            if (md[s] == 1)      win[rr][tx + 1] = bf2f(*sp[s]);
            else if (md[s] == 2) win[rr][tx + 1] = xr_p[s][0] * xe_me[0] * invv;
        }
        __syncthreads();
        if (act) {
            float a0 = bls[0], a1 = bls[1], a2 = bls[2], a3 = bls[3];
            #pragma unroll
            for (int kh = 0; kh < 4; ++kh) {
                #pragma unroll
                for (int kw = 0; kw < 3; ++kw) {
                    float v = win[2 * ty + kh][tx + kw];
                    a0 += v * wls[kh * 3 + kw];
                    a1 += v * wls[12 + kh * 3 + kw];
                    a2 += v * wls[24 + kh * 3 + kw];
                    a3 += v * wls[36 + kh * 3 + kw];
                }
            }
            float fg = sigm(a0), ig = sigm(a1), og = sigm(a2), cs = tanhs(a3);
            c_reg = fg * c_reg + ig * cs;
            float hn = og * tanhs(c_reg);
            *hp = f2bf(hn);
            pr = fmaxf(pr, hn);
        }
        hp += SLAB;
        xe_me += DD;
        #pragma unroll
        for (int s = 0; s < 3; ++s) {
            if (md[s] == 1) sp[s] += SLAB;
            else if (md[s] == 2) xr_p[s] += DD;
        }
    }
    if (pool && act)
        pool[(size_t)sb * PLANE + (size_t)(row0 + ty) * DD + tx] = pr;
}

// ---------------- tail: rows 111..127 serial, own rows in LDS ping-pong ----------------
// grid (NSB), block (128, 8). Input h rows 93..110 from global (t-1), 111..127 from LDS.
__global__ __launch_bounds__(1024)
void tail_kernel(const float* __restrict__ conv_w, const float* __restrict__ conv_b,
                 u16* __restrict__ h_own, float* __restrict__ pool, int layer) {
    const int sb = blockIdx.x;
    const int tx = threadIdx.x, ty = threadIdx.y;
    const int tid = ty * 128 + tx;
    __shared__ float win[2][36][130];   // local row lr = concat_h_row - 93; lr 35 = zero pad
    __shared__ float wls[48], bls[4];
    if (tid < 48) wls[tid] = conv_w[layer * 48 + tid];
    if (tid < 4)  bls[tid] = conv_b[layer * 4 + tid];
    for (int e = tid; e < 2 * 36 * 130; e += 1024) ((float*)win)[e] = 0.f;

    const u16* sp0 = h_own + (size_t)sb * PLANE + (size_t)(93 + ty) * DD + tx;   // slab t => t-1
    const u16* sp1 = sp0 + 8 * DD;
    const u16* sp2 = sp0 + 16 * DD;                    // used only for ty<2
    u16* hp0 = h_own + SLAB + (size_t)sb * PLANE + (size_t)(111 + ty) * DD + tx;
    u16* hp1 = hp0 + 8 * DD;
    u16* hp2 = hp0 + (size_t)(16 - ty) * DD;           // row 127 (ty==0 only)
    const bool wr_h = (layer == 0);                    // h2 tail rows never re-read
    float c0 = 0.f, c1 = 0.f, c2 = 0.f;
    float pr0 = -1e30f, pr1 = -1e30f, pr2 = -1e30f;

    for (int t = 0; t < LL; ++t) {
        const int p = t & 1;
        __syncthreads();               // prev compute done; prev reads done
        win[p][ty][tx + 1] = bf2f(*sp0);
        win[p][ty + 8][tx + 1] = bf2f(*sp1);
        if (ty < 2) win[p][ty + 16][tx + 1] = bf2f(*sp2);
        __syncthreads();

        #pragma unroll
        for (int slot = 0; slot < 3; ++slot) {
            if (slot == 2 && ty != 0) break;
            const int lr0 = (slot == 0) ? 2 * ty : (slot == 1 ? 16 + 2 * ty : 32);
            float a0 = bls[0], a1 = bls[1], a2 = bls[2], a3 = bls[3];
            #pragma unroll
            for (int kh = 0; kh < 4; ++kh) {
                #pragma unroll
                for (int kw = 0; kw < 3; ++kw) {
                    float v = win[p][lr0 + kh][tx + kw];
                    a0 += v * wls[kh * 3 + kw];
                    a1 += v * wls[12 + kh * 3 + kw];
                    a2 += v * wls[24 + kh * 3 + kw];
                    a3 += v * wls[36 + kh * 3 + kw];
                }
            }
            float fg = sigm(a0), ig = sigm(a1), og = sigm(a2), cs = tanhs(a3);
            float& cc = (slot == 0) ? c0 : (slot == 1 ? c1 : c2);
            float& pr = (slot == 0) ? pr0 : (slot == 1 ? pr1 : pr2);
            cc = fg * cc + ig * cs;
            float hn = og * tanhs(cc);
            const int own_lr = (slot == 0) ? 18 + ty : (slot == 1 ? 26 + ty : 34);
            win[p ^ 1][own_lr][tx + 1] = hn;
            if (wr_h) {
                u16* hp = (slot == 0) ? hp0 : (slot == 1 ? hp1 : hp2);
                *hp = f2bf(hn);
            }
            pr = fmaxf(pr, hn);
        }
        sp0 += SLAB; sp1 += SLAB; sp2 += SLAB;
        hp0 += SLAB; hp1 += SLAB; hp2 += SLAB;
    }
    if (layer == 1) {
        float* pb = pool + (size_t)sb * PLANE;
        pb[(size_t)(111 + ty) * DD + tx] = pr0;
        pb[(size_t)(119 + ty) * DD + tx] = pr1;
        if (ty == 0) pb[(size_t)127 * DD + tx] = pr2;
    }
}

// ---------------- final: linear + log_softmax ----------------
__global__ void final_kernel(const float* __restrict__ pool,
                             const float* __restrict__ lin_w,
                             const float* __restrict__ lin_b,
                             float* __restrict__ out) {
    const int b = blockIdx.x;
    const int tid = threadIdx.x;  // 256
    const int DD2 = DD * DD;
    const float* pq = pool + (size_t)b * DD2;
    const float* pa = pool + (size_t)(BB + b) * DD2;
    float s0 = 0.f, s1 = 0.f;
    for (int j = tid; j < DD2; j += 256) {
        float vq = pq[j], va = pa[j];
        s0 += vq * lin_w[j]           + va * lin_w[DD2 + j];
        s1 += vq * lin_w[2 * DD2 + j] + va * lin_w[3 * DD2 + j];
    }
    #pragma unroll
    for (int o = 32; o; o >>= 1) {
        s0 += __shfl_down(s0, o);
        s1 += __shfl_down(s1, o);
    }
    __shared__ float sh0[4], sh1[4];
    int wid = tid >> 6, lane = tid & 63;
    if (lane == 0) { sh0[wid] = s0; sh1[wid] = s1; }
    __syncthreads();
    if (tid == 0) {
        float a0 = sh0[0] + sh0[1] + sh0[2] + sh0[3] + lin_b[0];
        float a1 = sh1[0] + sh1[1] + sh1[2] + sh1[3] + lin_b[1];
        float m = fmaxf(a0, a1);
        float lse = m + logf(expf(a0 - m) + expf(a1 - m));
        out[b * 2 + 0] = a0 - lse;
        out[b * 2 + 1] = a1 - lse;
    }
}

extern "C" void kernel_launch(void* const* d_in, const int* in_sizes, int n_in,
                              void* d_out, int out_size, void* d_ws, size_t ws_size,
                              hipStream_t stream) {
    const int*   q      = (const int*)d_in[0];
    const int*   a      = (const int*)d_in[1];
    const float* embed  = (const float*)d_in[2];
    const float* conv_w = (const float*)d_in[3];
    const float* conv_b = (const float*)d_in[4];
    const float* lin_w  = (const float*)d_in[5];
    const float* lin_b  = (const float*)d_in[6];
    float* out = (float*)d_out;

    // ws: xe_all 1.31MB | inv_all | pool 4.2MB | h1 (41 slabs bf16, 86MB) | h2 86MB  => ~178MB
    float* ws      = (float*)d_ws;
    float* xe_all  = ws;
    float* inv_all = xe_all + (size_t)NU * DD;
    float* pool    = inv_all + NU;
    u16*   h1      = (u16*)(pool + (size_t)NSB * PLANE);
    u16*   h2      = h1 + (size_t)(LL + 1) * SLAB;

    // zero the leading (t = -1) slab of each h buffer
    hipMemsetAsync(h1, 0, SLAB * sizeof(u16), stream);
    hipMemsetAsync(h2, 0, SLAB * sizeof(u16), stream);

    prep_kernel<<<(NU + 3) / 4, 256, 0, stream>>>(q, a, embed, xe_all, inv_all);

    const dim3 blk(128, 8);
    // ---- layer 1 ----
    lev0_l1_kernel<<<dim3(8, NSB), blk, 0, stream>>>(xe_all, inv_all, conv_w, conv_b, h1);
    conv_level_kernel<<<dim3(4, NSB), blk, 0, stream>>>(xe_all, inv_all, conv_w, conv_b,
                                                        nullptr, h1, nullptr, 0, 63, 32);
    conv_level_kernel<<<dim3(2, NSB), blk, 0, stream>>>(xe_all, inv_all, conv_w, conv_b,
                                                        nullptr, h1, nullptr, 0, 95, 16);
    tail_kernel<<<NSB, blk, 0, stream>>>(conv_w, conv_b, h1, nullptr, 0);
    // ---- layer 2 ----
    conv_level_kernel<<<dim3(8, NSB), blk, 0, stream>>>(xe_all, inv_all, conv_w, conv_b,
                                                        h1, h2, pool, 1, 0, 63);
    conv_level_kernel<<<dim3(4, NSB), blk, 0, stream>>>(xe_all, inv_all, conv_w, conv_b,
                                                        h1, h2, pool, 1, 63, 32);
    conv_level_kernel<<<dim3(2, NSB), blk, 0, stream>>>(xe_all, inv_all, conv_w, conv_b,
                                                        h1, h2, pool, 1, 95, 16);
    tail_kernel<<<NSB, blk, 0, stream>>>(conv_w, conv_b, h2, pool, 1);

    final_kernel<<<BB, 256, 0, stream>>>(pool, lin_w, lin_b, out);
}